// Round 1
// 5437.531 us; speedup vs baseline: 1.2614x; 1.2614x over previous
//
#include <hip/hip_runtime.h>
#include <cstddef>
#include <cstdint>

// SDCN GNN: 5 × (dense GEMM + sparse A@· ) + softmax.
// Key identities used:
//   A@(F@W) = (A@F)@W  → layer-3 SpMM runs on the 500-wide input, not 2000-wide.
//   t4 = (0.5*relu(g3@W3)+0.5*tra3)@W4 is split:
//     gemm34:  t4  = 0.5*relu(g3@W3)@W4   (register-fused epilogue, barrier-free)
//     tra3w4:  t4 += 0.5*tra3@W4          (memory-bound streaming kernel)
//   h3 (50000x2000, 400MB) is never materialized.
// SpMM uses on-device CSR (built per launch) — no float atomics.

constexpr int D_IN = 512;   // input width
constexpr int D1   = 500;   // enc1 width (= wide SpMM width)
constexpr int D2   = 500;   // enc2 width
constexpr int D3   = 2000;  // enc3 width
constexpr int DC   = 10;    // z / cluster width

// ---------------------------------------------------------------- CSR build
__global__ void zero_i32(int* __restrict__ p, int n) {
    int i = blockIdx.x * 256 + threadIdx.x;
    if (i < n) p[i] = 0;
}

__global__ void count_edges(const int* __restrict__ row, int E, int* __restrict__ cnt) {
    int e = blockIdx.x * 256 + threadIdx.x;
    if (e < E) atomicAdd(&cnt[row[e]], 1);
}

// single-block exclusive scan over cnt[0..Nr) -> rp (and a copy into cur)
__global__ __launch_bounds__(1024) void scan_rowptr(const int* __restrict__ cnt, int Nr,
                                                    int* __restrict__ rp, int* __restrict__ cur) {
    __shared__ int sb[1024];
    const int t = threadIdx.x;
    int carry = 0;
    for (int base = 0; base < Nr; base += 1024) {
        int idx = base + t;
        int c = (idx < Nr) ? cnt[idx] : 0;
        sb[t] = c;
        __syncthreads();
        for (int off = 1; off < 1024; off <<= 1) {
            int add = (t >= off) ? sb[t - off] : 0;
            __syncthreads();
            sb[t] += add;
            __syncthreads();
        }
        if (idx < Nr) { int ex = carry + sb[t] - c; rp[idx] = ex; cur[idx] = ex; }
        carry += sb[1023];
        __syncthreads();
    }
    if (t == 0) rp[Nr] = carry;
}

__global__ void scatter_edges(const int* __restrict__ row, const int* __restrict__ col,
                              const float* __restrict__ val, int E,
                              int* __restrict__ cur, int* __restrict__ ci,
                              float* __restrict__ cv) {
    int e = blockIdx.x * 256 + threadIdx.x;
    if (e < E) {
        int r = row[e];
        int p = atomicAdd(&cur[r], 1);
        ci[p] = col[e];
        cv[p] = val[e];
    }
}

// ---------------------------------------------------------------- dense GEMM
// C(MxN) = A(MxK) @ B(KxN), fp32 row-major, 64x64 tile, 4x4 per thread.
constexpr int BM = 64, BN = 64, BK = 16;

__global__ __launch_bounds__(256) void gemm_tiled(const float* __restrict__ A,
                                                  const float* __restrict__ B,
                                                  float* __restrict__ C,
                                                  int M, int K, int Nn) {
    __shared__ float As[BM][BK + 1];
    __shared__ float Bs[BK][BN];
    const int tid = threadIdx.x;
    const int tx = tid & 15, ty = tid >> 4;
    const int rowBase = blockIdx.y * BM, colBase = blockIdx.x * BN;
    float acc[4][4] = {};
    for (int k0 = 0; k0 < K; k0 += BK) {
        for (int e = tid; e < BM * BK; e += 256) {
            int m = e >> 4, k = e & 15;
            int gr = rowBase + m, gk = k0 + k;
            As[m][k] = (gr < M && gk < K) ? A[(size_t)gr * K + gk] : 0.f;
        }
        for (int e = tid; e < BK * BN; e += 256) {
            int k = e >> 6, n = e & 63;
            int gk = k0 + k, gc = colBase + n;
            Bs[k][n] = (gk < K && gc < Nn) ? B[(size_t)gk * Nn + gc] : 0.f;
        }
        __syncthreads();
        for (int k = 0; k < BK; k++) {
            float a[4], b[4];
#pragma unroll
            for (int i = 0; i < 4; i++) a[i] = As[ty * 4 + i][k];
#pragma unroll
            for (int j = 0; j < 4; j++) b[j] = Bs[k][tx * 4 + j];
#pragma unroll
            for (int i = 0; i < 4; i++)
#pragma unroll
                for (int j = 0; j < 4; j++) acc[i][j] += a[i] * b[j];
        }
        __syncthreads();
    }
#pragma unroll
    for (int i = 0; i < 4; i++) {
        int gr = rowBase + ty * 4 + i;
        if (gr >= M) continue;
#pragma unroll
        for (int j = 0; j < 4; j++) {
            int gc = colBase + tx * 4 + j;
            if (gc < Nn) C[(size_t)gr * Nn + gc] = acc[i][j];
        }
    }
}

// ---------------------------------------------------- fused gemm3+relu+gemm4
// t4[i,c] = 0.5 * sum_j relu((g3@W3)[i,j]) * W4[j,c]
// Barrier-free: LDS holds only the g3 stripe (20 rows, full K=500, 40000 B).
// Wave w owns rows 5w..5w+4; lane owns 4 W3 columns per 256-wide j-chunk.
// P never leaves registers: relu + @W4 accumulate into acc[5][10], then one
// 64-lane shuffle butterfly at the very end. W3 ping-pong prefetched.
constexpr int R3  = 20;   // rows per block (50000 % 20 == 0)
constexpr int JB  = 256;  // j-chunk (64 lanes x 4 cols)

__global__ __launch_bounds__(256, 3) void gemm34(const float* __restrict__ g3,
                                                 const float* __restrict__ W3,
                                                 const float* __restrict__ W4,
                                                 float* __restrict__ t4) {
    __shared__ float gs[R3 * D2];     // 40000 B
    const int t = threadIdx.x;
    const size_t i0 = (size_t)blockIdx.x * R3;

    {   // cooperative stripe load, float4-vectorized (R3*D2/4 = 2500)
        const float4* src = reinterpret_cast<const float4*>(g3 + i0 * D2);
        float4* dst = reinterpret_cast<float4*>(gs);
        for (int e = t; e < R3 * D2 / 4; e += 256) dst[e] = src[e];
    }
    __syncthreads();   // the only barrier in this kernel

    const int lane = t & 63;
    const int rb = (t >> 6) * 5;       // wave's first row
    float acc[5][10] = {};

    for (int j0 = 0; j0 < D3; j0 += JB) {
        const int jb = min(JB, D3 - j0);   // 256,...,256,208
        const int j4 = lane * 4;
        if (j4 < jb) {
            float pacc[5][4] = {};
            const float* w3p = W3 + j0 + j4;
            float4 wa[4], wb[4];

            auto load_w3 = [&](float4 (&dst)[4], int k) {
#pragma unroll
                for (int kk = 0; kk < 4; kk++)
                    dst[kk] = *reinterpret_cast<const float4*>(w3p + (k + kk) * D3);
            };
            auto fma_grp = [&](const float4 (&wv)[4], int k) {
                float4 ga[5];
#pragma unroll
                for (int i = 0; i < 5; i++)   // wave-uniform addr → LDS broadcast
                    ga[i] = *reinterpret_cast<const float4*>(&gs[(rb + i) * D2 + k]);
#pragma unroll
                for (int kk = 0; kk < 4; kk++)
#pragma unroll
                    for (int i = 0; i < 5; i++) {
                        const float av = reinterpret_cast<const float*>(&ga[i])[kk];
#pragma unroll
                        for (int jj = 0; jj < 4; jj++)
                            pacc[i][jj] += av * reinterpret_cast<const float*>(&wv[kk])[jj];
                    }
            };

            // 125 k-groups of 4: 62 ping-pong iterations + 1 tail group
            load_w3(wa, 0);
            for (int k = 0; k < D2 - 4; k += 8) {
                load_w3(wb, k + 4);   // prefetch
                fma_grp(wa, k);
                load_w3(wa, k + 8);   // prefetch
                fma_grp(wb, k + 4);
            }
            fma_grp(wa, D2 - 4);      // k = 496

            // epilogue: relu + tiny W4 contraction, all in registers
#pragma unroll
            for (int jj = 0; jj < 4; jj++) {
                const float* w4r = W4 + (j0 + j4 + jj) * DC;
                float w4v[10];
#pragma unroll
                for (int h = 0; h < 5; h++) {   // 40-byte rows → float2 aligned
                    float2 u = *reinterpret_cast<const float2*>(w4r + 2 * h);
                    w4v[2 * h] = u.x;
                    w4v[2 * h + 1] = u.y;
                }
#pragma unroll
                for (int i = 0; i < 5; i++) {
                    const float p = fmaxf(pacc[i][jj], 0.f);
#pragma unroll
                    for (int c = 0; c < 10; c++) acc[i][c] += p * w4v[c];
                }
            }
        }
    }

    // sum each acc[i][c] over the 64 lanes (each lane covered a j-subset)
#pragma unroll
    for (int i = 0; i < 5; i++)
#pragma unroll
        for (int c = 0; c < 10; c++) {
            float v = acc[i][c];
            v += __shfl_xor(v, 1, 64);
            v += __shfl_xor(v, 2, 64);
            v += __shfl_xor(v, 4, 64);
            v += __shfl_xor(v, 8, 64);
            v += __shfl_xor(v, 16, 64);
            v += __shfl_xor(v, 32, 64);
            acc[i][c] = v;
        }
    if (lane == 0) {
        float* dst = t4 + (i0 + rb) * DC;
#pragma unroll
        for (int i = 0; i < 5; i++)
#pragma unroll
            for (int c = 0; c < 10; c++) dst[i * DC + c] = 0.5f * acc[i][c];
    }
}

// t4 += 0.5 * tra3 @ W4  — streaming, memory-bound (reads tra3 once, 400 MB).
// 16 rows/block; 16 lanes per row split j; shuffle-reduce within 16-lane group.
constexpr int RT = 16;

__global__ __launch_bounds__(256) void tra3w4(const float* __restrict__ tra3,
                                              const float* __restrict__ W4,
                                              float* __restrict__ t4) {
    const int t = threadIdx.x;
    const int r = t >> 4, l = t & 15;
    const size_t i = (size_t)blockIdx.x * RT + r;
    const float* rowp = tra3 + i * D3;
    float a[10] = {};
    for (int m = l; m < D3 / 4; m += 16) {   // coalesced float4, lane-interleaved
        float4 v = *reinterpret_cast<const float4*>(rowp + m * 4);
        const float* w4r = W4 + m * 4 * DC;
        const float vv[4] = {v.x, v.y, v.z, v.w};
#pragma unroll
        for (int q = 0; q < 4; q++)
#pragma unroll
            for (int c = 0; c < 10; c++) a[c] += vv[q] * w4r[q * DC + c];
    }
#pragma unroll
    for (int c = 0; c < 10; c++) {   // reduce across the 16 lanes of this row
        float v = a[c];
        v += __shfl_xor(v, 1, 64);
        v += __shfl_xor(v, 2, 64);
        v += __shfl_xor(v, 4, 64);
        v += __shfl_xor(v, 8, 64);
        a[c] = v;
    }
    if (l == 0) {
        float* dst = t4 + i * DC;
#pragma unroll
        for (int c = 0; c < 10; c++) dst[c] += 0.5f * a[c];
    }
}

// ---------------------------------------------------------------- SpMM (CSR)
// wide (width = 500): one block per row, 256 threads, <=2 cols per thread
__global__ __launch_bounds__(256) void spmm_w(const int* __restrict__ rp,
                                              const int* __restrict__ ci,
                                              const float* __restrict__ cv,
                                              const float* __restrict__ m,
                                              float* __restrict__ out,
                                              const float* __restrict__ mix,
                                              int relu) {
    const int i = blockIdx.x, t = threadIdx.x;
    const int c0 = t, c1 = t + 256;  // c1 valid for t < D1-256
    float a0 = 0.f, a1 = 0.f;
    const int pb = rp[i], pe = rp[i + 1];
    for (int p = pb; p < pe; p++) {
        const int col = ci[p];
        const float v = cv[p];
        const float* mr = m + (size_t)col * D1;
        a0 += v * mr[c0];
        if (c1 < D1) a1 += v * mr[c1];
    }
    if (relu) { a0 = fmaxf(a0, 0.f); a1 = fmaxf(a1, 0.f); }
    const size_t o = (size_t)i * D1;
    if (mix) {
        out[o + c0] = 0.5f * a0 + 0.5f * mix[o + c0];
        if (c1 < D1) out[o + c1] = 0.5f * a1 + 0.5f * mix[o + c1];
    } else {
        out[o + c0] = a0;
        if (c1 < D1) out[o + c1] = a1;
    }
}

// narrow (width = 10): 25 rows per block, thread = (row, col)
__global__ __launch_bounds__(256) void spmm_n(const int* __restrict__ rp,
                                              const int* __restrict__ ci,
                                              const float* __restrict__ cv,
                                              const float* __restrict__ m,
                                              float* __restrict__ out,
                                              const float* __restrict__ mix,
                                              int relu, int Nr) {
    const int t = threadIdx.x;
    const int lr = t / DC, c = t - lr * DC;
    if (lr >= 25) return;
    const int i = blockIdx.x * 25 + lr;
    if (i >= Nr) return;
    float a = 0.f;
    const int pb = rp[i], pe = rp[i + 1];
    for (int p = pb; p < pe; p++) a += cv[p] * m[(size_t)ci[p] * DC + c];
    if (relu) a = fmaxf(a, 0.f);
    if (mix) a = 0.5f * a + 0.5f * mix[(size_t)i * DC + c];
    out[(size_t)i * DC + c] = a;
}

// ---------------------------------------------------------------- softmax
__global__ void softmax10(const float* __restrict__ in, float* __restrict__ out, int Nr) {
    int i = blockIdx.x * 256 + threadIdx.x;
    if (i >= Nr) return;
    const float* r = in + (size_t)i * DC;
    float v[DC], mx = r[0];
#pragma unroll
    for (int c = 0; c < DC; c++) { v[c] = r[c]; mx = fmaxf(mx, v[c]); }
    float s = 0.f;
#pragma unroll
    for (int c = 0; c < DC; c++) { v[c] = __expf(v[c] - mx); s += v[c]; }
    float inv = 1.0f / s;
    float* o = out + (size_t)i * DC;
#pragma unroll
    for (int c = 0; c < DC; c++) o[c] = v[c] * inv;
}

// ---------------------------------------------------------------- launcher
extern "C" void kernel_launch(void* const* d_in, const int* in_sizes, int n_in,
                              void* d_out, int out_size, void* d_ws, size_t ws_size,
                              hipStream_t stream) {
    const float* x    = (const float*)d_in[0];
    const float* tra1 = (const float*)d_in[1];
    const float* tra2 = (const float*)d_in[2];
    const float* tra3 = (const float*)d_in[3];
    const float* z    = (const float*)d_in[4];
    const float* ev   = (const float*)d_in[5];
    const int*   erow = (const int*)d_in[6];
    const int*   ecol = (const int*)d_in[7];
    const float* W1   = (const float*)d_in[8];
    const float* W2   = (const float*)d_in[9];
    const float* W3   = (const float*)d_in[10];
    const float* W4   = (const float*)d_in[11];
    const float* W5   = (const float*)d_in[12];

    const int Nr = in_sizes[4] / DC;  // 50000
    const int E  = in_sizes[5];       // 1600000

    // workspace layout (~220 MB total)
    char* ws = (char*)d_ws;
    size_t off = 0;
    auto alloc = [&](size_t bytes) -> char* {
        char* p = ws + off;
        off = (off + bytes + 255) & ~(size_t)255;
        return p;
    };
    float* B0  = (float*)alloc((size_t)Nr * D1 * 4);      // 100 MB ping
    float* B1  = (float*)alloc((size_t)Nr * D1 * 4);      // 100 MB pong
    float* t4  = (float*)alloc((size_t)Nr * DC * 4);
    float* a4  = (float*)alloc((size_t)Nr * DC * 4);
    float* g5  = (float*)alloc((size_t)Nr * DC * 4);
    float* pre = (float*)alloc((size_t)Nr * DC * 4);
    int*   rp  = (int*)alloc((size_t)(Nr + 1) * 4);
    int*   cur = (int*)alloc((size_t)Nr * 4);
    int*   cnt = (int*)alloc((size_t)Nr * 4);
    int*   ci  = (int*)alloc((size_t)E * 4);
    float* cv  = (float*)alloc((size_t)E * 4);

    const int eb = (E + 255) / 256;
    const int nb = (Nr + 255) / 256;

    // CSR build
    zero_i32<<<nb, 256, 0, stream>>>(cnt, Nr);
    count_edges<<<eb, 256, 0, stream>>>(erow, E, cnt);
    scan_rowptr<<<1, 1024, 0, stream>>>(cnt, Nr, rp, cur);
    scatter_edges<<<eb, 256, 0, stream>>>(erow, ecol, ev, E, cur, ci, cv);

    auto gg = [&](int M, int Nn) { return dim3((Nn + BN - 1) / BN, (M + BM - 1) / BM); };

    // L1: h1' = 0.5*relu(A@(x@W1)) + 0.5*tra1
    gemm_tiled<<<gg(Nr, D1), 256, 0, stream>>>(x, W1, B0, Nr, D_IN, D1);
    spmm_w<<<Nr, 256, 0, stream>>>(rp, ci, cv, B0, B1, tra1, 1);
    // L2: h2' = 0.5*relu(A@(h1'@W2)) + 0.5*tra2
    gemm_tiled<<<gg(Nr, D2), 256, 0, stream>>>(B1, W2, B0, Nr, D1, D2);
    spmm_w<<<Nr, 256, 0, stream>>>(rp, ci, cv, B0, B1, tra2, 1);
    // L3 (SpMM first): g3 = A@h2'
    spmm_w<<<Nr, 256, 0, stream>>>(rp, ci, cv, B1, B0, nullptr, 0);
    // L3 GEMM + relu + L4 GEMM, register-fused: t4 = 0.5*relu(g3@W3)@W4
    gemm34<<<Nr / R3, 256, 0, stream>>>(B0, W3, W4, t4);
    // t4 += 0.5*tra3@W4 (streaming)
    tra3w4<<<Nr / RT, 256, 0, stream>>>(tra3, W4, t4);
    // L4 SpMM: a4 = 0.5*relu(A@t4) + 0.5*z
    spmm_n<<<(Nr + 24) / 25, 256, 0, stream>>>(rp, ci, cv, t4, a4, z, 1, Nr);
    // L5: pre = A@(a4@W5)
    gemm_tiled<<<gg(Nr, DC), 256, 0, stream>>>(a4, W5, g5, Nr, DC, DC);
    spmm_n<<<(Nr + 24) / 25, 256, 0, stream>>>(rp, ci, cv, g5, pre, nullptr, 0, Nr);
    // softmax
    softmax10<<<nb, 256, 0, stream>>>(pre, (float*)d_out, Nr);
}